// Round 8
// baseline (267.883 us; speedup 1.0000x reference)
//
#include <hip/hip_runtime.h>
#include <stdint.h>

typedef unsigned int uint;
typedef unsigned long long ull;

#define HW 3600
#define NBATCH 2
#define CDIM 256
#define KNN 64
#define M_REAL 7200
#define QPB 8              // topk queries per block (one per wave)

#define TKB 900            // topk blocks
#define IHB 904            // init_h blocks (2 c-tiles each)
#define SUB 96             // setup blocks (w1/w2 conversion, one float4/thread)

using short8  = __attribute__((ext_vector_type(8))) short;
using floatx4 = __attribute__((ext_vector_type(4))) float;

__device__ inline unsigned short f2bf(float f) {   // RNE fp32 -> bf16 bits
    uint u = __float_as_uint(f);
    uint r = u + 0x7FFFu + ((u >> 16) & 1u);
    return (unsigned short)(r >> 16);
}
__device__ inline float bf2f(unsigned short b) {
    return __uint_as_float(((uint)b) << 16);
}

// ---------------------------------------------------------------------------
// wave_select: find threshold byte-bin from a 256-bin wave-private histogram.
// ---------------------------------------------------------------------------
__device__ inline void wave_select(uint* hist, uint* s_bin, uint* s_want,
                                   int lane, uint want) {
    uint h0 = hist[4 * lane + 0], h1 = hist[4 * lane + 1];
    uint h2 = hist[4 * lane + 2], h3 = hist[4 * lane + 3];
    hist[4 * lane + 0] = 0; hist[4 * lane + 1] = 0;
    hist[4 * lane + 2] = 0; hist[4 * lane + 3] = 0;
    uint c4 = h0 + h1 + h2 + h3;
    uint v = c4;
    #pragma unroll
    for (int off = 1; off < 64; off <<= 1) {
        uint o = __shfl_up(v, off, 64);
        if (lane >= off) v += o;
    }
    uint below = v - c4;                 // count in bins < 4*lane
    if (below < want && want <= v) {     // threshold bin is in my 4 bins
        uint b = 4 * lane, c = below;
        if (c + h0 < want) { c += h0; b = 4 * lane + 1;
            if (c + h1 < want) { c += h1; b = 4 * lane + 2;
                if (c + h2 < want) { c += h2; b = 4 * lane + 3; } } }
        *s_bin = b;
        *s_want = want - c;
    }
}

// ---------------------------------------------------------------------------
// Mega-kernel, 512-thread blocks, three independent block-range roles:
//  [0,900)        topk (8 queries/block, 1/wave); exact fp32 d2 kept in
//                 57 VGPRs -> tie phase is register-only (no LDS rescan).
//  [900,1804)     init_h: h0 bf16 (7200x256 row-major) + fp32 passthrough
//  [1804,1900)    setup: build w1 = [mlp_w ; rnn_w[:, :256]] (512x256) and
//                 w2 = rnn_w[:, 256:] (256x256) in bf16
// ---------------------------------------------------------------------------
union MegaSmem {
    struct {
        float4 pts[HW];                  // 57600 B (x,y,z,pad)
        uint hist[QPB][256];             // 8192 B
        uint s_bin[QPB], s_want[QPB], s_cnt[QPB];
    } tk;
    struct { float tile[2][32][33]; } ih;
};

__global__ __launch_bounds__(512) void mega_kernel(
    const float* __restrict__ points, int* __restrict__ idx_out,
    const float* __restrict__ cnn, unsigned short* __restrict__ H,
    float* __restrict__ out,
    const float* __restrict__ mw, const float* __restrict__ rw,
    unsigned short* __restrict__ w1, unsigned short* __restrict__ w2) {
    __shared__ MegaSmem sm;
    const int blk = blockIdx.x;

    if (blk >= TKB + IHB) {
        // ---- setup role: one float4 per thread ----
        int idx4 = (blk - TKB - IHB) * 512 + threadIdx.x;    // [0, 49152)
        const float* src;
        unsigned short* dst;
        if (idx4 < 32768) {              // w1: n = j>>8, k = j&255
            int j = idx4 * 4;
            int n = j >> 8, k = j & 255;
            src = (n < 256) ? &mw[(size_t)n * 256 + k]
                            : &rw[(size_t)(n - 256) * 512 + k];
            dst = &w1[j];
        } else {                         // w2: Wr[n][k] = rnn_w[n][256+k]
            int j = (idx4 - 32768) * 4;
            int n = j >> 8, k = j & 255;
            src = &rw[(size_t)n * 512 + 256 + k];
            dst = &w2[j];
        }
        float4 vv = *(const float4*)src;
        uint2 p;
        p.x = (uint)f2bf(vv.x) | ((uint)f2bf(vv.y) << 16);
        p.y = (uint)f2bf(vv.z) | ((uint)f2bf(vv.w) << 16);
        *(uint2*)dst = p;
        return;
    }

    if (blk >= TKB) {
        // ---- init_h role: two 32x32 c-tiles per block ----
        const int b = blk - TKB;             // 0..903
        const int n = b / 452;
        const int r = b - n * 452;
        const int hw0 = (r % 113) * 32;
        const int c0 = (r / 113) * 64 + ((threadIdx.x >> 8) << 5);
        const int t8 = threadIdx.x & 255;
        const int tx = t8 & 31;
        const int ty = t8 >> 5;              // 0..7
        float (*tile)[33] = sm.ih.tile[threadIdx.x >> 8];
        const float* __restrict__ src = cnn + (size_t)n * CDIM * HW;
        #pragma unroll
        for (int rr = 0; rr < 4; ++rr) {
            int cc = ty + rr * 8;
            int hw = hw0 + tx;
            if (hw < HW) {
                float v = src[(size_t)(c0 + cc) * HW + hw];
                tile[cc][tx] = v;
                out[(size_t)n * (2 * CDIM * HW) + (size_t)(c0 + cc) * HW + hw] = v;
            }
        }
        __syncthreads();
        #pragma unroll
        for (int rr = 0; rr < 4; ++rr) {
            int hh = ty + rr * 8;
            int hw = hw0 + hh;
            if (hw < HW)
                H[(size_t)(n * HW + hw) * CDIM + c0 + tx] = f2bf(tile[tx][hh]);
        }
        return;
    }

    // ---- topk role ----
    const int wv = threadIdx.x >> 6;
    const int lane = threadIdx.x & 63;
    const int q = blk * QPB + wv;
    const int n = (blk * QPB) / HW;          // batch uniform per block (450 | 8)
    const int i = q - n * HW;

    const float* __restrict__ px = points + (size_t)n * 3 * HW;
    const float* __restrict__ py = px + HW;
    const float* __restrict__ pz = py + HW;

    for (int j = threadIdx.x; j < HW; j += 512)
        sm.tk.pts[j] = make_float4(px[j], py[j], pz[j], 0.0f);
    sm.tk.hist[wv][4 * lane + 0] = 0; sm.tk.hist[wv][4 * lane + 1] = 0;
    sm.tk.hist[wv][4 * lane + 2] = 0; sm.tk.hist[wv][4 * lane + 3] = 0;
    if (lane == 0) sm.tk.s_cnt[wv] = 0;
    __syncthreads();

    float4 pq = sm.tk.pts[i];
    const float xi = pq.x, yi = pq.y, zi = pq.z;
    const float sqi = xi * xi + yi * yi + zi * zi;

    // distances once (one b128/point): exact fp32 in regs + packed q16
    float d2v[57];
    uint qp[29];
    #pragma unroll
    for (int s = 0; s < 57; ++s) {
        int j = (s << 6) + lane;
        float d2 = 1e30f;                    // OOB sentinel (strip 56 only)
        if (j < HW) {
            float4 p = sm.tk.pts[j];
            d2 = fmaxf(sqi + (p.x * p.x + p.y * p.y + p.z * p.z)
                       - 2.0f * (xi * p.x + yi * p.y + zi * p.z), 0.0f);
        }
        d2v[s] = d2;
        uint q16 = (uint)fminf(d2 * 1024.0f, 65535.0f);
        if (s & 1) qp[s >> 1] |= q16 << 16; else qp[s >> 1] = q16;
    }
    #define Q16(s) ((qp[(s) >> 1] >> (((s) & 1) << 4)) & 0xFFFFu)

    // pass 1: high byte (predicated: no OOB same-bin serialization)
    #pragma unroll
    for (int s = 0; s < 57; ++s) {
        int j = (s << 6) + lane;
        if (j < HW) atomicAdd(&sm.tk.hist[wv][Q16(s) >> 8], 1u);
    }
    __syncthreads();
    wave_select(&sm.tk.hist[wv][0], &sm.tk.s_bin[wv], &sm.tk.s_want[wv], lane, KNN);
    __syncthreads();
    const uint qT8 = sm.tk.s_bin[wv];
    const uint want2 = sm.tk.s_want[wv];
    __syncthreads();

    // pass 2: low byte among survivors
    #pragma unroll
    for (int s = 0; s < 57; ++s) {
        int j = (s << 6) + lane;
        uint k = Q16(s);
        if (j < HW && (k >> 8) == qT8)
            atomicAdd(&sm.tk.hist[wv][k & 255u], 1u);
    }
    __syncthreads();
    wave_select(&sm.tk.hist[wv][0], &sm.tk.s_bin[wv], &sm.tk.s_want[wv], lane, want2);
    __syncthreads();
    const uint qT16 = (qT8 << 8) | sm.tk.s_bin[wv];
    const uint want3 = sm.tk.s_want[wv];

    // collect all strictly-below (sentinels 0xFFFF never pass)
    #pragma unroll
    for (int s = 0; s < 57; ++s) {
        if (Q16(s) < qT16) {
            uint pos = atomicAdd(&sm.tk.s_cnt[wv], 1u);
            if (pos < KNN) idx_out[(size_t)q * KNN + pos] = (s << 6) + lane;
        }
    }
    // ties at qT16: exact (f32bits(d2),index) min from REGISTERS, want3 rounds
    ull used = 0ULL;
    const int base = KNN - (int)want3;
    for (int r = 0; r < (int)want3; ++r) {
        ull best = ~0ULL;
        #pragma unroll
        for (int s = 0; s < 57; ++s) {
            int j = (s << 6) + lane;
            if (j < HW && Q16(s) == qT16 && !((used >> s) & 1ULL)) {
                ull key = ((ull)__float_as_uint(d2v[s]) << 32) | (uint)j;
                if (key < best) best = key;
            }
        }
        #pragma unroll
        for (int off = 1; off < 64; off <<= 1) {
            ull o = __shfl_xor(best, off, 64);
            if (o < best) best = o;
        }
        uint jw = (uint)best;
        if (lane == 0) idx_out[(size_t)q * KNN + base + r] = (int)jw;
        if ((int)(jw & 63u) == lane) used |= 1ULL << (jw >> 6);
    }
    #undef Q16
}

// ---------------------------------------------------------------------------
// Fused per-iteration GEMM, register-direct (no global->LDS staging):
//   t = relu(h . Wm^T + mlp_b)   (LDS-resident only)
//   v = h . Wl^T                 (stored bf16; bias/relu deferred to gather)
//   u = t . Wr^T                 (stored bf16)
// Block = 16 rows x 8 waves; frag A/B = 16 contiguous K-bytes per lane, so
// both operands load straight from row-major global (L2-resident weights).
// 7200/16 = 450 blocks exactly (no pad rows anywhere).
// ---------------------------------------------------------------------------
#define LDT 264
__global__ __launch_bounds__(512) void fused_gemm(
    const unsigned short* __restrict__ h,    // 7200 x 256
    const unsigned short* __restrict__ w1,   // 512 x 256  [Wm ; Wl]
    const unsigned short* __restrict__ w2,   // 256 x 256  Wr
    const float* __restrict__ mlp_b,
    unsigned short* __restrict__ u,          // 7200 x 256
    unsigned short* __restrict__ v) {        // 7200 x 256
    __shared__ __align__(16) unsigned short ts[16 * LDT];
    const int m0 = blockIdx.x * 16;
    const int lane = threadIdx.x & 63;
    const int w = threadIdx.x >> 6;          // 0..7
    const int l15 = lane & 15;
    const int qd = lane >> 4;

    // stage 1: s1 = h . w1^T ; wave w covers cols w*64..+64 (4 frags)
    floatx4 acc1[4];
    #pragma unroll
    for (int f = 0; f < 4; ++f) acc1[f] = (floatx4){0.f, 0.f, 0.f, 0.f};
    const int col0 = w * 64;
    #pragma unroll
    for (int k0 = 0; k0 < 256; k0 += 32) {
        short8 a = *(const short8*)&h[(size_t)(m0 + l15) * 256 + k0 + qd * 8];
        #pragma unroll
        for (int nf = 0; nf < 4; ++nf) {
            short8 b = *(const short8*)
                &w1[(size_t)(col0 + nf * 16 + l15) * 256 + k0 + qd * 8];
            acc1[nf] = __builtin_amdgcn_mfma_f32_16x16x32_bf16(a, b, acc1[nf], 0, 0, 0);
        }
    }
    if (w < 4) {                             // t half: relu+bias -> LDS
        #pragma unroll
        for (int nf = 0; nf < 4; ++nf) {
            int c = col0 + nf * 16 + l15;
            float bb = mlp_b[c];
            #pragma unroll
            for (int r = 0; r < 4; ++r)
                ts[(qd * 4 + r) * LDT + c] = f2bf(fmaxf(acc1[nf][r] + bb, 0.0f));
        }
    } else {                                 // v half -> global bf16
        #pragma unroll
        for (int nf = 0; nf < 4; ++nf) {
            int c = col0 - 256 + nf * 16 + l15;
            #pragma unroll
            for (int r = 0; r < 4; ++r)
                v[(size_t)(m0 + qd * 4 + r) * 256 + c] = f2bf(acc1[nf][r]);
        }
    }
    __syncthreads();

    // stage 2: u = t . w2^T ; wave w covers cols w*32..+32 (2 frags)
    floatx4 acc2[2];
    acc2[0] = (floatx4){0.f, 0.f, 0.f, 0.f};
    acc2[1] = (floatx4){0.f, 0.f, 0.f, 0.f};
    const int uc0 = w * 32;
    #pragma unroll
    for (int k0 = 0; k0 < 256; k0 += 32) {
        short8 a = *(const short8*)&ts[l15 * LDT + k0 + qd * 8];
        #pragma unroll
        for (int nf = 0; nf < 2; ++nf) {
            short8 b = *(const short8*)
                &w2[(size_t)(uc0 + nf * 16 + l15) * 256 + k0 + qd * 8];
            acc2[nf] = __builtin_amdgcn_mfma_f32_16x16x32_bf16(a, b, acc2[nf], 0, 0, 0);
        }
    }
    #pragma unroll
    for (int nf = 0; nf < 2; ++nf) {
        int c = uc0 + nf * 16 + l15;
        #pragma unroll
        for (int r = 0; r < 4; ++r)
            u[(size_t)(m0 + qd * 4 + r) * 256 + c] = f2bf(acc2[nf][r]);
    }
}

// ---------------------------------------------------------------------------
// gather + RNN epilogue: h'[q] = relu( v[q] + mean_k u[idx[q][k]] + rnn_b )
// wave per query: 32 lanes x 8 cols (uint4 loads), k parity by lane-half,
// shfl_xor(32) cross-half reduce. Gathered index clamped (fault guard).
// ---------------------------------------------------------------------------
__global__ __launch_bounds__(256) void gather_rnn(
    const unsigned short* __restrict__ u, const unsigned short* __restrict__ v,
    const int* __restrict__ idx, const float* __restrict__ rnn_b,
    unsigned short* __restrict__ hout) {
    const int q = blockIdx.x * 4 + (threadIdx.x >> 6);
    const int lane = threadIdx.x & 63;
    const int n = q / HW;
    const int half = lane >> 5;           // k parity
    const int c8 = (lane & 31) * 8;       // 8-col strip

    const int nbrL = idx[(size_t)q * KNN + lane];
    float acc[8] = {0, 0, 0, 0, 0, 0, 0, 0};
    #pragma unroll 4
    for (int it = 0; it < 32; ++it) {
        int j = __shfl(nbrL, 2 * it + half, 64);
        j = min(max(j, 0), HW - 1);       // defensive clamp
        uint4 t4 = *(const uint4*)&u[(size_t)(n * HW + j) * 256 + c8];
        acc[0] += bf2f((unsigned short)(t4.x & 0xFFFFu));
        acc[1] += bf2f((unsigned short)(t4.x >> 16));
        acc[2] += bf2f((unsigned short)(t4.y & 0xFFFFu));
        acc[3] += bf2f((unsigned short)(t4.y >> 16));
        acc[4] += bf2f((unsigned short)(t4.z & 0xFFFFu));
        acc[5] += bf2f((unsigned short)(t4.z >> 16));
        acc[6] += bf2f((unsigned short)(t4.w & 0xFFFFu));
        acc[7] += bf2f((unsigned short)(t4.w >> 16));
    }
    #pragma unroll
    for (int c = 0; c < 8; ++c) acc[c] += __shfl_xor(acc[c], 32, 64);
    if (half == 0) {
        uint4 vv = *(const uint4*)&v[(size_t)q * 256 + c8];
        float4 b0 = *(const float4*)&rnn_b[c8];
        float4 b1 = *(const float4*)&rnn_b[c8 + 4];
        float hv[8];
        hv[0] = fmaxf(bf2f((unsigned short)(vv.x & 0xFFFFu)) + acc[0] * (1.0f / KNN) + b0.x, 0.0f);
        hv[1] = fmaxf(bf2f((unsigned short)(vv.x >> 16))     + acc[1] * (1.0f / KNN) + b0.y, 0.0f);
        hv[2] = fmaxf(bf2f((unsigned short)(vv.y & 0xFFFFu)) + acc[2] * (1.0f / KNN) + b0.z, 0.0f);
        hv[3] = fmaxf(bf2f((unsigned short)(vv.y >> 16))     + acc[3] * (1.0f / KNN) + b0.w, 0.0f);
        hv[4] = fmaxf(bf2f((unsigned short)(vv.z & 0xFFFFu)) + acc[4] * (1.0f / KNN) + b1.x, 0.0f);
        hv[5] = fmaxf(bf2f((unsigned short)(vv.z >> 16))     + acc[5] * (1.0f / KNN) + b1.y, 0.0f);
        hv[6] = fmaxf(bf2f((unsigned short)(vv.w & 0xFFFFu)) + acc[6] * (1.0f / KNN) + b1.z, 0.0f);
        hv[7] = fmaxf(bf2f((unsigned short)(vv.w >> 16))     + acc[7] * (1.0f / KNN) + b1.w, 0.0f);
        uint4 o;
        o.x = (uint)f2bf(hv[0]) | ((uint)f2bf(hv[1]) << 16);
        o.y = (uint)f2bf(hv[2]) | ((uint)f2bf(hv[3]) << 16);
        o.z = (uint)f2bf(hv[4]) | ((uint)f2bf(hv[5]) << 16);
        o.w = (uint)f2bf(hv[6]) | ((uint)f2bf(hv[7]) << 16);
        *(uint4*)&hout[(size_t)q * 256 + c8] = o;
    }
}

// out[n][256 + c][hw] = fp32(h3[(n*HW+hw)*256 + c])
__global__ __launch_bounds__(256) void final_out(const unsigned short* __restrict__ Hf,
                                                 float* __restrict__ out) {
    __shared__ float tile[32][33];
    const int hw0 = blockIdx.x * 32;
    const int c0 = blockIdx.y * 32;
    const int n = blockIdx.z;
    const int tx = threadIdx.x & 31;
    const int ty = threadIdx.x >> 5;
    #pragma unroll
    for (int r = 0; r < 4; ++r) {
        int hh = ty + r * 8;
        int hw = hw0 + hh;
        if (hw < HW) tile[hh][tx] = bf2f(Hf[(size_t)(n * HW + hw) * CDIM + c0 + tx]);
    }
    __syncthreads();
    #pragma unroll
    for (int r = 0; r < 4; ++r) {
        int cc = ty + r * 8;
        int hw = hw0 + tx;
        if (hw < HW)
            out[(size_t)n * (2 * CDIM * HW) + (size_t)(CDIM + c0 + cc) * HW + hw] =
                tile[tx][cc];
    }
}

extern "C" void kernel_launch(void* const* d_in, const int* in_sizes, int n_in,
                              void* d_out, int out_size, void* d_ws, size_t ws_size,
                              hipStream_t stream) {
    const float* cnn   = (const float*)d_in[0];
    const float* pts   = (const float*)d_in[1];
    const float* mlp_w = (const float*)d_in[2];
    const float* mlp_b = (const float*)d_in[3];
    const float* rnn_w = (const float*)d_in[4];
    const float* rnn_b = (const float*)d_in[5];
    float* out = (float*)d_out;

    // workspace (all bf16 7200x256 planes):
    // ha | hb | u | v | w1(512x256) | w2(256x256) | idx(7200x64 int)
    unsigned short* ha = (unsigned short*)d_ws;
    unsigned short* hb = ha + (size_t)M_REAL * 256;
    unsigned short* ub = hb + (size_t)M_REAL * 256;
    unsigned short* vb = ub + (size_t)M_REAL * 256;
    unsigned short* w1 = vb + (size_t)M_REAL * 256;
    unsigned short* w2 = w1 + 131072;
    int*            idx = (int*)(w2 + 65536);

    mega_kernel<<<TKB + IHB + SUB, 512, 0, stream>>>(
        pts, idx, cnn, ha, out, mlp_w, rnn_w, w1, w2);

    unsigned short* cur = ha;
    unsigned short* nxt = hb;
    for (int it = 0; it < 3; ++it) {
        fused_gemm<<<M_REAL / 16, 512, 0, stream>>>(cur, w1, w2, mlp_b, ub, vb);
        gather_rnn<<<M_REAL / 4, 256, 0, stream>>>(ub, vb, idx, rnn_b, nxt);
        unsigned short* tmp = cur; cur = nxt; nxt = tmp;
    }

    final_out<<<dim3(113, 8, NBATCH), 256, 0, stream>>>(cur, out);
}

// Round 10
// 229.523 us; speedup vs baseline: 1.1671x; 1.1671x over previous
//
#include <hip/hip_runtime.h>
#include <stdint.h>

typedef unsigned int uint;
typedef unsigned long long ull;

#define HW 3600
#define NBATCH 2
#define CDIM 256
#define KNN 64
#define M_REAL 7200
#define PADM 7232          // 7200 padded to multiple of 64 (113*64)
#define QPB 8              // topk queries per block (one per wave)

#define TKB 900            // topk blocks
#define IHB 904            // init_h blocks (2 c-tiles each)
#define SUB 96             // setup blocks (w1/w2 build, one float4/thread)

using short8  = __attribute__((ext_vector_type(8))) short;
using floatx4 = __attribute__((ext_vector_type(4))) float;

__device__ inline unsigned short f2bf(float f) {   // RNE fp32 -> bf16 bits
    uint u = __float_as_uint(f);
    uint r = u + 0x7FFFu + ((u >> 16) & 1u);
    return (unsigned short)(r >> 16);
}
__device__ inline float bf2f(unsigned short b) {
    return __uint_as_float(((uint)b) << 16);
}

// ---------------------------------------------------------------------------
// wave_select: find threshold byte-bin from a 256-bin wave-private histogram.
// ---------------------------------------------------------------------------
__device__ inline void wave_select(uint* hist, uint* s_bin, uint* s_want,
                                   int lane, uint want) {
    uint h0 = hist[4 * lane + 0], h1 = hist[4 * lane + 1];
    uint h2 = hist[4 * lane + 2], h3 = hist[4 * lane + 3];
    hist[4 * lane + 0] = 0; hist[4 * lane + 1] = 0;
    hist[4 * lane + 2] = 0; hist[4 * lane + 3] = 0;
    uint c4 = h0 + h1 + h2 + h3;
    uint v = c4;
    #pragma unroll
    for (int off = 1; off < 64; off <<= 1) {
        uint o = __shfl_up(v, off, 64);
        if (lane >= off) v += o;
    }
    uint below = v - c4;                 // count in bins < 4*lane
    if (below < want && want <= v) {     // threshold bin is in my 4 bins
        uint b = 4 * lane, c = below;
        if (c + h0 < want) { c += h0; b = 4 * lane + 1;
            if (c + h1 < want) { c += h1; b = 4 * lane + 2;
                if (c + h2 < want) { c += h2; b = 4 * lane + 3; } } }
        *s_bin = b;
        *s_want = want - c;
    }
}

// ---------------------------------------------------------------------------
// Mega-kernel (r7-proven topk), 512-thread blocks, three roles:
//  [0,900)      topk: 8 queries/block (1/wave), AoS float4 points in LDS
//  [900,1804)   init_h: h0 bf16 (7200x256 row-major) + fp32 passthrough
//  [1804,1900)  setup: w1 = [mlp_w ; rnn_w[:, :256]] (512x256),
//               w2 = rnn_w[:, 256:] (256x256), bf16
// ---------------------------------------------------------------------------
union MegaSmem {
    struct {
        float4 pts[HW];                  // 57600 B (x,y,z,pad)
        uint hist[QPB][256];             // 8192 B
        uint s_bin[QPB], s_want[QPB], s_cnt[QPB];
    } tk;
    struct { float tile[2][32][33]; } ih;
};

__global__ __launch_bounds__(512) void mega_kernel(
    const float* __restrict__ points, int* __restrict__ idx_out,
    const float* __restrict__ cnn, unsigned short* __restrict__ H,
    float* __restrict__ out,
    const float* __restrict__ mw, const float* __restrict__ rw,
    unsigned short* __restrict__ w1, unsigned short* __restrict__ w2) {
    __shared__ MegaSmem sm;
    const int blk = blockIdx.x;

    if (blk >= TKB + IHB) {
        // ---- setup role: one float4 per thread ----
        int idx4 = (blk - TKB - IHB) * 512 + threadIdx.x;    // [0, 49152)
        const float* src;
        unsigned short* dst;
        if (idx4 < 32768) {              // w1
            int j = idx4 * 4;
            int n = j >> 8, k = j & 255;
            src = (n < 256) ? &mw[(size_t)n * 256 + k]
                            : &rw[(size_t)(n - 256) * 512 + k];
            dst = &w1[j];
        } else {                         // w2: Wr[n][k] = rnn_w[n][256+k]
            int j = (idx4 - 32768) * 4;
            int n = j >> 8, k = j & 255;
            src = &rw[(size_t)n * 512 + 256 + k];
            dst = &w2[j];
        }
        float4 vv = *(const float4*)src;
        uint2 p;
        p.x = (uint)f2bf(vv.x) | ((uint)f2bf(vv.y) << 16);
        p.y = (uint)f2bf(vv.z) | ((uint)f2bf(vv.w) << 16);
        *(uint2*)dst = p;
        return;
    }

    if (blk >= TKB) {
        // ---- init_h role: two 32x32 c-tiles per block ----
        const int b = blk - TKB;             // 0..903
        const int n = b / 452;
        const int r = b - n * 452;
        const int hw0 = (r % 113) * 32;
        const int c0 = (r / 113) * 64 + ((threadIdx.x >> 8) << 5);
        const int t8 = threadIdx.x & 255;
        const int tx = t8 & 31;
        const int ty = t8 >> 5;              // 0..7
        float (*tile)[33] = sm.ih.tile[threadIdx.x >> 8];
        const float* __restrict__ src = cnn + (size_t)n * CDIM * HW;
        #pragma unroll
        for (int rr = 0; rr < 4; ++rr) {
            int cc = ty + rr * 8;
            int hw = hw0 + tx;
            if (hw < HW) {
                float v = src[(size_t)(c0 + cc) * HW + hw];
                tile[cc][tx] = v;
                out[(size_t)n * (2 * CDIM * HW) + (size_t)(c0 + cc) * HW + hw] = v;
            }
        }
        __syncthreads();
        #pragma unroll
        for (int rr = 0; rr < 4; ++rr) {
            int hh = ty + rr * 8;
            int hw = hw0 + hh;
            if (hw < HW)
                H[(size_t)(n * HW + hw) * CDIM + c0 + tx] = f2bf(tile[tx][hh]);
        }
        return;
    }

    // ---- topk role (r7 verbatim) ----
    const int wv = threadIdx.x >> 6;
    const int lane = threadIdx.x & 63;
    const int q = blk * QPB + wv;
    const int n = (blk * QPB) / HW;          // batch uniform per block (450 | 8)
    const int i = q - n * HW;

    const float* __restrict__ px = points + (size_t)n * 3 * HW;
    const float* __restrict__ py = px + HW;
    const float* __restrict__ pz = py + HW;

    for (int j = threadIdx.x; j < HW; j += 512)
        sm.tk.pts[j] = make_float4(px[j], py[j], pz[j], 0.0f);
    sm.tk.hist[wv][4 * lane + 0] = 0; sm.tk.hist[wv][4 * lane + 1] = 0;
    sm.tk.hist[wv][4 * lane + 2] = 0; sm.tk.hist[wv][4 * lane + 3] = 0;
    if (lane == 0) sm.tk.s_cnt[wv] = 0;
    __syncthreads();

    float4 pq = sm.tk.pts[i];
    const float xi = pq.x, yi = pq.y, zi = pq.z;
    const float sqi = xi * xi + yi * yi + zi * zi;

    // distances + quantize once (one b128/point); pack q16 pairs (29 VGPRs)
    uint qp[29];
    #pragma unroll
    for (int s = 0; s < 57; ++s) {
        int j = (s << 6) + lane;
        uint q16 = 0xFFFFu;                  // OOB sentinel (strip 56 only)
        if (j < HW) {
            float4 p = sm.tk.pts[j];
            float d2 = fmaxf(sqi + (p.x * p.x + p.y * p.y + p.z * p.z)
                             - 2.0f * (xi * p.x + yi * p.y + zi * p.z), 0.0f);
            q16 = (uint)fminf(d2 * 1024.0f, 65535.0f);
        }
        if (s & 1) qp[s >> 1] |= q16 << 16; else qp[s >> 1] = q16;
    }
    #define Q16(s) ((qp[(s) >> 1] >> (((s) & 1) << 4)) & 0xFFFFu)

    // pass 1: high byte (predicated: no OOB same-bin atomic serialization)
    #pragma unroll
    for (int s = 0; s < 57; ++s) {
        int j = (s << 6) + lane;
        if (j < HW) atomicAdd(&sm.tk.hist[wv][Q16(s) >> 8], 1u);
    }
    __syncthreads();
    wave_select(&sm.tk.hist[wv][0], &sm.tk.s_bin[wv], &sm.tk.s_want[wv], lane, KNN);
    __syncthreads();
    const uint qT8 = sm.tk.s_bin[wv];
    const uint want2 = sm.tk.s_want[wv];
    __syncthreads();

    // pass 2: low byte among survivors
    #pragma unroll
    for (int s = 0; s < 57; ++s) {
        int j = (s << 6) + lane;
        uint k = Q16(s);
        if (j < HW && (k >> 8) == qT8)
            atomicAdd(&sm.tk.hist[wv][k & 255u], 1u);
    }
    __syncthreads();
    wave_select(&sm.tk.hist[wv][0], &sm.tk.s_bin[wv], &sm.tk.s_want[wv], lane, want2);
    __syncthreads();
    const uint qT16 = (qT8 << 8) | sm.tk.s_bin[wv];
    const uint want3 = sm.tk.s_want[wv];

    // collect all strictly-below (sentinels 0xFFFF never pass)
    #pragma unroll
    for (int s = 0; s < 57; ++s) {
        if (Q16(s) < qT16) {
            uint pos = atomicAdd(&sm.tk.s_cnt[wv], 1u);
            if (pos < KNN) idx_out[(size_t)q * KNN + pos] = (s << 6) + lane;
        }
    }
    // ties at qT16: exact (f32bits(d2),index) min recomputed from LDS
    ull used = 0ULL;
    const int base = KNN - (int)want3;
    for (int r = 0; r < (int)want3; ++r) {
        ull best = ~0ULL;
        #pragma unroll
        for (int s = 0; s < 57; ++s) {
            int j = (s << 6) + lane;
            if (j < HW && Q16(s) == qT16 && !((used >> s) & 1ULL)) {
                float4 p = sm.tk.pts[j];
                float d2 = fmaxf(sqi + (p.x * p.x + p.y * p.y + p.z * p.z)
                                 - 2.0f * (xi * p.x + yi * p.y + zi * p.z), 0.0f);
                ull key = ((ull)__float_as_uint(d2) << 32) | (uint)j;
                if (key < best) best = key;
            }
        }
        #pragma unroll
        for (int off = 1; off < 64; off <<= 1) {
            ull o = __shfl_xor(best, off, 64);
            if (o < best) best = o;
        }
        uint jw = (uint)best;
        if (lane == 0) idx_out[(size_t)q * KNN + base + r] = (int)jw;
        if ((int)(jw & 63u) == lane) used |= 1ULL << (jw >> 6);
    }
    #undef Q16
}

// ---------------------------------------------------------------------------
// bf16 MFMA GEMM (r7-proven body, K=256 fixed, lda=ldw=256):
// 64x64 tile, full-K staging, 4 waves x 32x32 (2x2 frags of 16x16x32).
// mode 0 (dispatch A, grid 113x8): n0<256 -> Ct[m][n0..] = relu(acc+bias),
//                                  n0>=256 -> Cv[m][n0-256..] = acc (raw)
// mode 1 (dispatch B, grid 113x4): Ct[m][col] = acc (raw)
// ---------------------------------------------------------------------------
#define LDKP 264
__global__ __launch_bounds__(256) void gemm_mfma(
    const unsigned short* __restrict__ A,
    const unsigned short* __restrict__ W,
    const float* __restrict__ bias,
    unsigned short* __restrict__ Ct, unsigned short* __restrict__ Cv,
    int mode) {
    __shared__ __align__(16) unsigned short As[64 * LDKP];
    __shared__ __align__(16) unsigned short Bs[64 * LDKP];
    const int m0 = blockIdx.x * 64;
    const int n0 = blockIdx.y * 64;
    const int tid = threadIdx.x;
    const int lane = tid & 63;
    const int w = tid >> 6;
    const int wm = (w & 1) * 32;
    const int wn = (w >> 1) * 32;
    const int l15 = lane & 15;
    const int qd = lane >> 4;            // quad 0..3

    floatx4 acc[2][2];
    #pragma unroll
    for (int a = 0; a < 2; ++a)
        #pragma unroll
        for (int b = 0; b < 2; ++b)
            acc[a][b] = (floatx4){0.f, 0.f, 0.f, 0.f};

    const int srow = tid >> 5;           // 0..7
    const int scol = (tid & 31) * 8;     // 16B chunks across K=256

    #pragma unroll
    for (int r8 = 0; r8 < 8; ++r8) {
        int row = r8 * 8 + srow;
        *(float4*)&As[row * LDKP + scol] =
            *(const float4*)&A[(size_t)(m0 + row) * 256 + scol];
        *(float4*)&Bs[row * LDKP + scol] =
            *(const float4*)&W[(size_t)(n0 + row) * 256 + scol];
    }
    __syncthreads();
    #pragma unroll
    for (int ks = 0; ks < 256; ks += 32) {
        short8 a0 = *(const short8*)&As[(wm + l15) * LDKP + ks + qd * 8];
        short8 a1 = *(const short8*)&As[(wm + 16 + l15) * LDKP + ks + qd * 8];
        short8 b0 = *(const short8*)&Bs[(wn + l15) * LDKP + ks + qd * 8];
        short8 b1 = *(const short8*)&Bs[(wn + 16 + l15) * LDKP + ks + qd * 8];
        acc[0][0] = __builtin_amdgcn_mfma_f32_16x16x32_bf16(a0, b0, acc[0][0], 0, 0, 0);
        acc[0][1] = __builtin_amdgcn_mfma_f32_16x16x32_bf16(a0, b1, acc[0][1], 0, 0, 0);
        acc[1][0] = __builtin_amdgcn_mfma_f32_16x16x32_bf16(a1, b0, acc[1][0], 0, 0, 0);
        acc[1][1] = __builtin_amdgcn_mfma_f32_16x16x32_bf16(a1, b1, acc[1][1], 0, 0, 0);
    }

    #pragma unroll
    for (int in = 0; in < 2; ++in) {
        int col = n0 + wn + in * 16 + l15;
        #pragma unroll
        for (int im = 0; im < 2; ++im) {
            int mb = m0 + wm + im * 16 + qd * 4;
            if (mode == 0 && col < 256) {        // t: bias+relu (block-uniform)
                float bv = bias[col];
                #pragma unroll
                for (int r = 0; r < 4; ++r)
                    Ct[(size_t)(mb + r) * 256 + col] =
                        f2bf(fmaxf(acc[im][in][r] + bv, 0.0f));
            } else if (mode == 0) {              // v: raw
                #pragma unroll
                for (int r = 0; r < 4; ++r)
                    Cv[(size_t)(mb + r) * 256 + (col - 256)] =
                        f2bf(acc[im][in][r]);
            } else {                             // u: raw
                #pragma unroll
                for (int r = 0; r < 4; ++r)
                    Ct[(size_t)(mb + r) * 256 + col] = f2bf(acc[im][in][r]);
            }
        }
    }
}

// ---------------------------------------------------------------------------
// gather + RNN epilogue (r8-proven): h' = relu(v + mean_k u[idx] + rnn_b)
// wave per query: 32 lanes x 8 cols (uint4 loads), k parity by lane-half,
// shfl_xor(32) cross-half reduce. Final iteration stores fp32 transposed
// directly into out[n][256+c][hw].
// ---------------------------------------------------------------------------
__global__ __launch_bounds__(256) void gather_rnn(
    const unsigned short* __restrict__ u, const unsigned short* __restrict__ v,
    const int* __restrict__ idx, const float* __restrict__ rnn_b,
    unsigned short* __restrict__ hout, float* __restrict__ outp, int final_it) {
    const int q = blockIdx.x * 4 + (threadIdx.x >> 6);
    const int lane = threadIdx.x & 63;
    const int n = q / HW;
    const int half = lane >> 5;           // k parity
    const int c8 = (lane & 31) * 8;       // 8-col strip

    const int nbrL = idx[(size_t)q * KNN + lane];
    float acc[8] = {0, 0, 0, 0, 0, 0, 0, 0};
    #pragma unroll 4
    for (int it = 0; it < 32; ++it) {
        int j = __shfl(nbrL, 2 * it + half, 64);
        j = min(max(j, 0), HW - 1);       // defensive clamp
        uint4 t4 = *(const uint4*)&u[(size_t)(n * HW + j) * 256 + c8];
        acc[0] += bf2f((unsigned short)(t4.x & 0xFFFFu));
        acc[1] += bf2f((unsigned short)(t4.x >> 16));
        acc[2] += bf2f((unsigned short)(t4.y & 0xFFFFu));
        acc[3] += bf2f((unsigned short)(t4.y >> 16));
        acc[4] += bf2f((unsigned short)(t4.z & 0xFFFFu));
        acc[5] += bf2f((unsigned short)(t4.z >> 16));
        acc[6] += bf2f((unsigned short)(t4.w & 0xFFFFu));
        acc[7] += bf2f((unsigned short)(t4.w >> 16));
    }
    #pragma unroll
    for (int c = 0; c < 8; ++c) acc[c] += __shfl_xor(acc[c], 32, 64);
    if (half == 0) {
        uint4 vv = *(const uint4*)&v[(size_t)q * 256 + c8];
        float4 b0 = *(const float4*)&rnn_b[c8];
        float4 b1 = *(const float4*)&rnn_b[c8 + 4];
        float hv[8];
        hv[0] = fmaxf(bf2f((unsigned short)(vv.x & 0xFFFFu)) + acc[0] * (1.0f / KNN) + b0.x, 0.0f);
        hv[1] = fmaxf(bf2f((unsigned short)(vv.x >> 16))     + acc[1] * (1.0f / KNN) + b0.y, 0.0f);
        hv[2] = fmaxf(bf2f((unsigned short)(vv.y & 0xFFFFu)) + acc[2] * (1.0f / KNN) + b0.z, 0.0f);
        hv[3] = fmaxf(bf2f((unsigned short)(vv.y >> 16))     + acc[3] * (1.0f / KNN) + b0.w, 0.0f);
        hv[4] = fmaxf(bf2f((unsigned short)(vv.z & 0xFFFFu)) + acc[4] * (1.0f / KNN) + b1.x, 0.0f);
        hv[5] = fmaxf(bf2f((unsigned short)(vv.z >> 16))     + acc[5] * (1.0f / KNN) + b1.y, 0.0f);
        hv[6] = fmaxf(bf2f((unsigned short)(vv.w & 0xFFFFu)) + acc[6] * (1.0f / KNN) + b1.z, 0.0f);
        hv[7] = fmaxf(bf2f((unsigned short)(vv.w >> 16))     + acc[7] * (1.0f / KNN) + b1.w, 0.0f);
        if (!final_it) {
            uint4 o;
            o.x = (uint)f2bf(hv[0]) | ((uint)f2bf(hv[1]) << 16);
            o.y = (uint)f2bf(hv[2]) | ((uint)f2bf(hv[3]) << 16);
            o.z = (uint)f2bf(hv[4]) | ((uint)f2bf(hv[5]) << 16);
            o.w = (uint)f2bf(hv[6]) | ((uint)f2bf(hv[7]) << 16);
            *(uint4*)&hout[(size_t)q * 256 + c8] = o;
        } else {
            int hw = q - n * HW;
            float* ob = &outp[(size_t)n * (2 * CDIM * HW)
                              + (size_t)(CDIM + c8) * HW + hw];
            #pragma unroll
            for (int c = 0; c < 8; ++c) ob[(size_t)c * HW] = hv[c];
        }
    }
}

extern "C" void kernel_launch(void* const* d_in, const int* in_sizes, int n_in,
                              void* d_out, int out_size, void* d_ws, size_t ws_size,
                              hipStream_t stream) {
    const float* cnn   = (const float*)d_in[0];
    const float* pts   = (const float*)d_in[1];
    const float* mlp_w = (const float*)d_in[2];
    const float* mlp_b = (const float*)d_in[3];
    const float* rnn_w = (const float*)d_in[4];
    const float* rnn_b = (const float*)d_in[5];
    float* out = (float*)d_out;

    // workspace (bf16 7232x256 planes):
    // ha | hb | tb | vb | ub | w1(512x256) | w2(256x256) | idx(7200x64 int)
    unsigned short* ha = (unsigned short*)d_ws;
    unsigned short* hb = ha + (size_t)PADM * 256;
    unsigned short* tb = hb + (size_t)PADM * 256;
    unsigned short* vb = tb + (size_t)PADM * 256;
    unsigned short* ub = vb + (size_t)PADM * 256;
    unsigned short* w1 = ub + (size_t)PADM * 256;
    unsigned short* w2 = w1 + 131072;
    int*            idx = (int*)(w2 + 65536);

    mega_kernel<<<TKB + IHB + SUB, 512, 0, stream>>>(
        pts, idx, cnn, ha, out, mlp_w, rnn_w, w1, w2);

    unsigned short* cur = ha;
    unsigned short* nxt = hb;
    for (int it = 0; it < 3; ++it) {
        // [t; v] = h . [Wm; Wl]^T  (t: relu+bias, v: raw) — 904 blocks
        gemm_mfma<<<dim3(113, 8), 256, 0, stream>>>(cur, w1, mlp_b, tb, vb, 0);
        // u = t . Wr^T (raw) — 452 blocks
        gemm_mfma<<<dim3(113, 4), 256, 0, stream>>>(tb, w2, nullptr, ub, nullptr, 1);
        // h' = relu(v + mean_k u[idx] + rnn_b); final iter -> fp32 into out
        gather_rnn<<<M_REAL / 4, 256, 0, stream>>>(
            ub, vb, idx, rnn_b, nxt, out, it == 2 ? 1 : 0);
        unsigned short* tmp = cur; cur = nxt; nxt = tmp;
    }
}